// Round 3
// baseline (228.163 us; speedup 1.0000x reference)
//
#include <hip/hip_runtime.h>
#include <math.h>

#define DD 192
#define HH 192
#define WW 192
#define NVOX (DD*HH*WW)        // 7077888
#define NV4  (NVOX/4)          // 1769472
#define RB   1024              // reduction blocks
#define RT   256               // reduction threads per block

typedef float f32x4 __attribute__((ext_vector_type(4)));

struct Consts {
    float tx, ty, tz;          // grid translation
    float wgt[8];              // corner weights, index = dz*4+dy*2+dx
    int   dx0, dy0, dz0;       // integer corner offsets (floor of shift)
};

__device__ __forceinline__ float gcoord(int i, int n) {
    return -1.0f + (float)i * (2.0f / (float)(n - 1));
}

__device__ __forceinline__ f32x4 load4u(const float* p) {
    f32x4 v;
    __builtin_memcpy(&v, p, sizeof(v));   // 4B-aligned 16B load (gfx9+ HW supports)
    return v;
}

// quantities: 0:sum_x 1:sum x*gx 2:sum x*gy 3:sum x*gz  4..7: same for y
__global__ void reduce_kernel(const float* __restrict__ x,
                              const float* __restrict__ y,
                              double* __restrict__ partials) {
    double acc[8] = {0,0,0,0,0,0,0,0};
    int tid = blockIdx.x * blockDim.x + threadIdx.x;
    const float4* x4 = (const float4*)x;
    const float4* y4 = (const float4*)y;
    for (int i = tid; i < NV4; i += RB * RT) {
        float4 xv = x4[i];
        float4 yv = y4[i];
        int base = i * 4;
        int w = base % WW;          // multiple of 4
        int rem = base / WW;
        int h = rem % HH;
        int d = rem / HH;
        float gy = gcoord(h, HH);
        float gz = gcoord(d, DD);
        float xs[4] = {xv.x, xv.y, xv.z, xv.w};
        float ys[4] = {yv.x, yv.y, yv.z, yv.w};
        #pragma unroll
        for (int k = 0; k < 4; ++k) {
            float gx = gcoord(w + k, WW);
            acc[0] += (double)xs[k];
            acc[1] += (double)(xs[k] * gx);
            acc[2] += (double)(xs[k] * gy);
            acc[3] += (double)(xs[k] * gz);
            acc[4] += (double)ys[k];
            acc[5] += (double)(ys[k] * gx);
            acc[6] += (double)(ys[k] * gy);
            acc[7] += (double)(ys[k] * gz);
        }
    }
    #pragma unroll
    for (int q = 0; q < 8; ++q) {
        double v = acc[q];
        #pragma unroll
        for (int off = 32; off > 0; off >>= 1)
            v += __shfl_down(v, off, 64);
        acc[q] = v;
    }
    __shared__ double lds[4][8];
    int lane = threadIdx.x & 63;
    int wave = threadIdx.x >> 6;
    if (lane == 0) {
        #pragma unroll
        for (int q = 0; q < 8; ++q) lds[wave][q] = acc[q];
    }
    __syncthreads();
    if (threadIdx.x < 8) {
        int q = threadIdx.x;
        partials[q * RB + blockIdx.x] = lds[0][q] + lds[1][q] + lds[2][q] + lds[3][q];
    }
}

__global__ void finalize_kernel(const double* __restrict__ partials,
                                Consts* __restrict__ cs) {
    double s[8];
    #pragma unroll
    for (int q = 0; q < 8; ++q) {
        double v = 0.0;
        for (int i = threadIdx.x; i < RB; i += 256) v += partials[q * RB + i];
        #pragma unroll
        for (int off = 32; off > 0; off >>= 1)
            v += __shfl_down(v, off, 64);
        s[q] = v;
    }
    __shared__ double lds[4][8];
    int lane = threadIdx.x & 63;
    int wave = threadIdx.x >> 6;
    if (lane == 0) {
        #pragma unroll
        for (int q = 0; q < 8; ++q) lds[wave][q] = s[q];
    }
    __syncthreads();
    if (threadIdx.x == 0) {
        double sums[8];
        #pragma unroll
        for (int q = 0; q < 8; ++q)
            sums[q] = lds[0][q] + lds[1][q] + lds[2][q] + lds[3][q];
        double tx = sums[1] / sums[0] - sums[5] / sums[4];
        double ty = sums[2] / sums[0] - sums[6] / sums[4];
        double tz = sums[3] / sums[0] - sums[7] / sums[4];
        cs->tx = (float)tx; cs->ty = (float)ty; cs->tz = (float)tz;
        double cx = tx * (double)(WW - 1) * 0.5;
        double cy = ty * (double)(HH - 1) * 0.5;
        double cz = tz * (double)(DD - 1) * 0.5;
        double fx = floor(cx), fy = floor(cy), fz = floor(cz);
        float wx = (float)(cx - fx), wy = (float)(cy - fy), wz = (float)(cz - fz);
        cs->dx0 = (int)fx; cs->dy0 = (int)fy; cs->dz0 = (int)fz;
        #pragma unroll
        for (int k = 0; k < 8; ++k) {
            float wzz = (k & 4) ? wz : 1.0f - wz;
            float wyy = (k & 2) ? wy : 1.0f - wy;
            float wxx = (k & 1) ? wx : 1.0f - wx;
            cs->wgt[k] = wzz * wyy * wxx;
        }
    }
}

// Fused main: 4 voxels/thread. Grid written as 3 direct float4 NT stores;
// trilinear = constant-shift stencil, 2 loads per (z,y)-row per 4 voxels.
__global__ void __launch_bounds__(256) main_kernel(const float* __restrict__ x,
                                                   const Consts* __restrict__ csp,
                                                   f32x4* __restrict__ out_t4,
                                                   f32x4* __restrict__ out_g4) {
    const Consts c = *csp;                 // uniform address -> scalar loads
    int t = blockIdx.x * 256 + threadIdx.x; // group of 4 voxels (row-aligned: 192%4==0)
    int vb = t * 4;
    int w0 = vb % WW;
    int rem = vb / WW;
    int h = rem % HH;
    int d = rem / HH;

    float gx0 = gcoord(w0 + 0, WW) + c.tx;
    float gx1 = gcoord(w0 + 1, WW) + c.tx;
    float gx2 = gcoord(w0 + 2, WW) + c.tx;
    float gx3 = gcoord(w0 + 3, WW) + c.tx;
    float gy  = gcoord(h, HH) + c.ty;
    float gz  = gcoord(d, DD) + c.tz;
    f32x4 f0 = {gx0, gy, gz, gx1};
    f32x4 f1 = {gy, gz, gx2, gy};
    f32x4 f2 = {gz, gx3, gy, gz};
    __builtin_nontemporal_store(f0, &out_g4[3 * t + 0]);
    __builtin_nontemporal_store(f1, &out_g4[3 * t + 1]);
    __builtin_nontemporal_store(f2, &out_g4[3 * t + 2]);

    // y/z corner rows (uniform per thread)
    int yi0 = h + c.dy0, yi1 = yi0 + 1;
    int zi0 = d + c.dz0, zi1 = zi0 + 1;
    int ys0 = min(max(yi0, 0), HH - 1), ys1 = min(max(yi1, 0), HH - 1);
    int zs0 = min(max(zi0, 0), DD - 1), zs1 = min(max(zi1, 0), DD - 1);
    float vy0 = ((unsigned)yi0 < (unsigned)HH) ? 1.0f : 0.0f;
    float vy1 = ((unsigned)yi1 < (unsigned)HH) ? 1.0f : 0.0f;
    float vz0 = ((unsigned)zi0 < (unsigned)DD) ? 1.0f : 0.0f;
    float vz1 = ((unsigned)zi1 < (unsigned)DD) ? 1.0f : 0.0f;
    int   rb[4]  = { (zs0 * HH + ys0) * WW, (zs0 * HH + ys1) * WW,
                     (zs1 * HH + ys0) * WW, (zs1 * HH + ys1) * WW };
    float sr[4]  = { vz0 * vy0, vz0 * vy1, vz1 * vy0, vz1 * vy1 };

    int xi0g = w0 + c.dx0;                 // first corner x of the group
    f32x4 acc = {0.0f, 0.0f, 0.0f, 0.0f};

    if (xi0g >= 0 && xi0g + 4 <= WW - 1) {
        // fast path: all 5 x-positions in range -> vector loads, no x-validity
        #pragma unroll
        for (int r = 0; r < 4; ++r) {
            float w0r = sr[r] * c.wgt[2 * r + 0];
            float w1r = sr[r] * c.wgt[2 * r + 1];
            const float* p = x + rb[r] + xi0g;
            f32x4 v  = load4u(p);
            float v4 = p[4];
            acc.x += w0r * v.x + w1r * v.y;
            acc.y += w0r * v.y + w1r * v.z;
            acc.z += w0r * v.z + w1r * v.w;
            acc.w += w0r * v.w + w1r * v4;
        }
    } else {
        // slow path: x-boundary groups (<= 2 thread-columns of the volume)
        float res[4];
        #pragma unroll
        for (int k = 0; k < 4; ++k) {
            int xi0 = xi0g + k, xi1 = xi0 + 1;
            int xs0 = min(max(xi0, 0), WW - 1), xs1 = min(max(xi1, 0), WW - 1);
            float vx0 = ((unsigned)xi0 < (unsigned)WW) ? 1.0f : 0.0f;
            float vx1 = ((unsigned)xi1 < (unsigned)WW) ? 1.0f : 0.0f;
            float a = 0.0f;
            #pragma unroll
            for (int r = 0; r < 4; ++r) {
                a += x[rb[r] + xs0] * (sr[r] * c.wgt[2 * r + 0] * vx0);
                a += x[rb[r] + xs1] * (sr[r] * c.wgt[2 * r + 1] * vx1);
            }
            res[k] = a;
        }
        acc.x = res[0]; acc.y = res[1]; acc.z = res[2]; acc.w = res[3];
    }
    __builtin_nontemporal_store(acc, &out_t4[t]);
}

extern "C" void kernel_launch(void* const* d_in, const int* in_sizes, int n_in,
                              void* d_out, int out_size, void* d_ws, size_t ws_size,
                              hipStream_t stream) {
    const float* x = (const float*)d_in[0];
    const float* y = (const float*)d_in[1];
    float* out = (float*)d_out;
    f32x4* out_t4 = (f32x4*)out;             // transformed: NVOX floats (16B aligned)
    f32x4* out_g4 = (f32x4*)(out + NVOX);    // grid: NVOX*3 floats (28.3MB -> 16B aligned)
    double* partials = (double*)d_ws;        // 8*RB doubles = 64 KiB
    Consts* cs = (Consts*)((char*)d_ws + 8 * RB * sizeof(double));
    reduce_kernel<<<RB, RT, 0, stream>>>(x, y, partials);
    finalize_kernel<<<1, 256, 0, stream>>>(partials, cs);
    main_kernel<<<NVOX / 4 / 256, 256, 0, stream>>>(x, cs, out_t4, out_g4);
}

// Round 4
// 180.153 us; speedup vs baseline: 1.2665x; 1.2665x over previous
//
#include <hip/hip_runtime.h>
#include <math.h>

#define DD 192
#define HH 192
#define WW 192
#define NVOX (DD*HH*WW)        // 7077888
#define NV4  (NVOX/4)          // 1769472
#define RB   1024              // reduction blocks
#define RT   256               // reduction threads per block

typedef float f32x4 __attribute__((ext_vector_type(4)));

struct Consts {
    float tx, ty, tz;          // grid translation
    float wgt[8];              // corner weights, index = dz*4+dy*2+dx
    int   dx0, dy0, dz0;       // integer corner offsets (floor of shift)
};

__device__ __forceinline__ float gcoord(int i, int n) {
    return -1.0f + (float)i * (2.0f / (float)(n - 1));
}

__device__ __forceinline__ f32x4 load4u(const float* p) {
    f32x4 v;
    __builtin_memcpy(&v, p, sizeof(v));   // 4B-aligned 16B load
    return v;
}

// quantities: 0:sum_x 1:sum x*gx 2:sum x*gy 3:sum x*gz  4..7: same for y
__global__ void reduce_kernel(const float* __restrict__ x,
                              const float* __restrict__ y,
                              double* __restrict__ partials) {
    double acc[8] = {0,0,0,0,0,0,0,0};
    int tid = blockIdx.x * blockDim.x + threadIdx.x;
    const float4* x4 = (const float4*)x;
    const float4* y4 = (const float4*)y;
    for (int i = tid; i < NV4; i += RB * RT) {
        float4 xv = x4[i];
        float4 yv = y4[i];
        int base = i * 4;
        int w = base % WW;          // multiple of 4
        int rem = base / WW;
        int h = rem % HH;
        int d = rem / HH;
        float gy = gcoord(h, HH);
        float gz = gcoord(d, DD);
        float xs[4] = {xv.x, xv.y, xv.z, xv.w};
        float ys[4] = {yv.x, yv.y, yv.z, yv.w};
        #pragma unroll
        for (int k = 0; k < 4; ++k) {
            float gx = gcoord(w + k, WW);
            acc[0] += (double)xs[k];
            acc[1] += (double)(xs[k] * gx);
            acc[2] += (double)(xs[k] * gy);
            acc[3] += (double)(xs[k] * gz);
            acc[4] += (double)ys[k];
            acc[5] += (double)(ys[k] * gx);
            acc[6] += (double)(ys[k] * gy);
            acc[7] += (double)(ys[k] * gz);
        }
    }
    #pragma unroll
    for (int q = 0; q < 8; ++q) {
        double v = acc[q];
        #pragma unroll
        for (int off = 32; off > 0; off >>= 1)
            v += __shfl_down(v, off, 64);
        acc[q] = v;
    }
    __shared__ double lds[4][8];
    int lane = threadIdx.x & 63;
    int wave = threadIdx.x >> 6;
    if (lane == 0) {
        #pragma unroll
        for (int q = 0; q < 8; ++q) lds[wave][q] = acc[q];
    }
    __syncthreads();
    if (threadIdx.x < 8) {
        int q = threadIdx.x;
        partials[q * RB + blockIdx.x] = lds[0][q] + lds[1][q] + lds[2][q] + lds[3][q];
    }
}

__global__ void finalize_kernel(const double* __restrict__ partials,
                                Consts* __restrict__ cs) {
    double s[8];
    #pragma unroll
    for (int q = 0; q < 8; ++q) {
        double v = 0.0;
        for (int i = threadIdx.x; i < RB; i += 256) v += partials[q * RB + i];
        #pragma unroll
        for (int off = 32; off > 0; off >>= 1)
            v += __shfl_down(v, off, 64);
        s[q] = v;
    }
    __shared__ double lds[4][8];
    int lane = threadIdx.x & 63;
    int wave = threadIdx.x >> 6;
    if (lane == 0) {
        #pragma unroll
        for (int q = 0; q < 8; ++q) lds[wave][q] = s[q];
    }
    __syncthreads();
    if (threadIdx.x == 0) {
        double sums[8];
        #pragma unroll
        for (int q = 0; q < 8; ++q)
            sums[q] = lds[0][q] + lds[1][q] + lds[2][q] + lds[3][q];
        double tx = sums[1] / sums[0] - sums[5] / sums[4];
        double ty = sums[2] / sums[0] - sums[6] / sums[4];
        double tz = sums[3] / sums[0] - sums[7] / sums[4];
        cs->tx = (float)tx; cs->ty = (float)ty; cs->tz = (float)tz;
        double cx = tx * (double)(WW - 1) * 0.5;
        double cy = ty * (double)(HH - 1) * 0.5;
        double cz = tz * (double)(DD - 1) * 0.5;
        double fx = floor(cx), fy = floor(cy), fz = floor(cz);
        float wx = (float)(cx - fx), wy = (float)(cy - fy), wz = (float)(cz - fz);
        cs->dx0 = (int)fx; cs->dy0 = (int)fy; cs->dz0 = (int)fz;
        #pragma unroll
        for (int k = 0; k < 8; ++k) {
            float wzz = (k & 4) ? wz : 1.0f - wz;
            float wyy = (k & 2) ? wy : 1.0f - wy;
            float wxx = (k & 1) ? wx : 1.0f - wx;
            cs->wgt[k] = wzz * wyy * wxx;
        }
    }
}

// Fused main: 4 voxels/thread (1024 voxels/block).
// Grid: 12 floats/thread staged in LDS, stored as 3 lane-consecutive float4
// NT stores (full 1KB lines per instruction — no partial-line writeback).
// Trilinear: constant-shift stencil, vector loads on the interior fast path.
__global__ void __launch_bounds__(256) main_kernel(const float* __restrict__ x,
                                                   const Consts* __restrict__ csp,
                                                   f32x4* __restrict__ out_t4,
                                                   f32x4* __restrict__ out_g4) {
    __shared__ float gbuf[3072];           // 1024 voxels * 3 comps = 12 KB
    const Consts c = *csp;                 // uniform address -> scalar loads
    int t = blockIdx.x * 256 + threadIdx.x; // group of 4 voxels (row-aligned)
    int vb = t * 4;
    int w0 = vb % WW;
    int rem = vb / WW;
    int h = rem % HH;
    int d = rem / HH;

    float gx0 = gcoord(w0 + 0, WW) + c.tx;
    float gx1 = gcoord(w0 + 1, WW) + c.tx;
    float gx2 = gcoord(w0 + 2, WW) + c.tx;
    float gx3 = gcoord(w0 + 3, WW) + c.tx;
    float gy  = gcoord(h, HH) + c.ty;
    float gz  = gcoord(d, DD) + c.tz;
    {
        f32x4* myg = (f32x4*)&gbuf[threadIdx.x * 12];
        f32x4 f0 = {gx0, gy, gz, gx1};
        f32x4 f1 = {gy, gz, gx2, gy};
        f32x4 f2 = {gz, gx3, gy, gz};
        myg[0] = f0; myg[1] = f1; myg[2] = f2;
    }

    // y/z corner rows (uniform per thread)
    int yi0 = h + c.dy0, yi1 = yi0 + 1;
    int zi0 = d + c.dz0, zi1 = zi0 + 1;
    int ys0 = min(max(yi0, 0), HH - 1), ys1 = min(max(yi1, 0), HH - 1);
    int zs0 = min(max(zi0, 0), DD - 1), zs1 = min(max(zi1, 0), DD - 1);
    float vy0 = ((unsigned)yi0 < (unsigned)HH) ? 1.0f : 0.0f;
    float vy1 = ((unsigned)yi1 < (unsigned)HH) ? 1.0f : 0.0f;
    float vz0 = ((unsigned)zi0 < (unsigned)DD) ? 1.0f : 0.0f;
    float vz1 = ((unsigned)zi1 < (unsigned)DD) ? 1.0f : 0.0f;
    int   rb[4]  = { (zs0 * HH + ys0) * WW, (zs0 * HH + ys1) * WW,
                     (zs1 * HH + ys0) * WW, (zs1 * HH + ys1) * WW };
    float sr[4]  = { vz0 * vy0, vz0 * vy1, vz1 * vy0, vz1 * vy1 };

    int xi0g = w0 + c.dx0;                 // first corner x of the group
    f32x4 acc = {0.0f, 0.0f, 0.0f, 0.0f};

    if (xi0g >= 0 && xi0g + 4 <= WW - 1) {
        // fast path: all 5 x-positions in range
        #pragma unroll
        for (int r = 0; r < 4; ++r) {
            float w0r = sr[r] * c.wgt[2 * r + 0];
            float w1r = sr[r] * c.wgt[2 * r + 1];
            const float* p = x + rb[r] + xi0g;
            f32x4 v  = load4u(p);
            float v4 = p[4];
            acc.x += w0r * v.x + w1r * v.y;
            acc.y += w0r * v.y + w1r * v.z;
            acc.z += w0r * v.z + w1r * v.w;
            acc.w += w0r * v.w + w1r * v4;
        }
    } else {
        // slow path: x-boundary groups
        float res[4];
        #pragma unroll
        for (int k = 0; k < 4; ++k) {
            int xi0 = xi0g + k, xi1 = xi0 + 1;
            int xs0 = min(max(xi0, 0), WW - 1), xs1 = min(max(xi1, 0), WW - 1);
            float vx0 = ((unsigned)xi0 < (unsigned)WW) ? 1.0f : 0.0f;
            float vx1 = ((unsigned)xi1 < (unsigned)WW) ? 1.0f : 0.0f;
            float a = 0.0f;
            #pragma unroll
            for (int r = 0; r < 4; ++r) {
                a += x[rb[r] + xs0] * (sr[r] * c.wgt[2 * r + 0] * vx0);
                a += x[rb[r] + xs1] * (sr[r] * c.wgt[2 * r + 1] * vx1);
            }
            res[k] = a;
        }
        acc.x = res[0]; acc.y = res[1]; acc.z = res[2]; acc.w = res[3];
    }
    __builtin_nontemporal_store(acc, &out_t4[t]);

    // coalesced grid store: 3 x (64 lanes x 16B contiguous)
    __syncthreads();
    const f32x4* gsrc = (const f32x4*)gbuf;
    int gbase = blockIdx.x * 768;
    #pragma unroll
    for (int k = 0; k < 3; ++k) {
        int p = k * 256 + threadIdx.x;
        __builtin_nontemporal_store(gsrc[p], &out_g4[gbase + p]);
    }
}

extern "C" void kernel_launch(void* const* d_in, const int* in_sizes, int n_in,
                              void* d_out, int out_size, void* d_ws, size_t ws_size,
                              hipStream_t stream) {
    const float* x = (const float*)d_in[0];
    const float* y = (const float*)d_in[1];
    float* out = (float*)d_out;
    f32x4* out_t4 = (f32x4*)out;             // transformed: NVOX floats
    f32x4* out_g4 = (f32x4*)(out + NVOX);    // grid: NVOX*3 floats
    double* partials = (double*)d_ws;        // 8*RB doubles = 64 KiB
    Consts* cs = (Consts*)((char*)d_ws + 8 * RB * sizeof(double));
    reduce_kernel<<<RB, RT, 0, stream>>>(x, y, partials);
    finalize_kernel<<<1, 256, 0, stream>>>(partials, cs);
    main_kernel<<<NVOX / 4 / 256, 256, 0, stream>>>(x, cs, out_t4, out_g4);
}